// Round 1
// baseline (1791.322 us; speedup 1.0000x reference)
//
#include <hip/hip_runtime.h>
#include <hip/hip_bf16.h>

// Problem constants
#define BATCH 16
#define IN_C 3
#define Q_C 8
#define V_C 16
#define HH 224
#define WW 224
#define KK 7
#define H2 112
#define W2 112

// Padded layouts
#define XPH 230   // stored row = orig row + 3, orig rows -3..226 needed up to 228
#define XPW 232   // stored col = orig col + 3
#define QPH 118   // stored = orig + 3, orig -3..114
#define QPW 120

// Sizes (floats)
#define XPAD_N (BATCH*IN_C*XPH*XPW)            // 2,561,280
#define QPAD_N (BATCH*IN_C*Q_C*QPH*QPW)        // 5,437,440
#define VPAD_N (BATCH*V_C*QPH*QPW)             // 3,624,960
#define A_N    (BATCH*IN_C*V_C*16)             // 12,288
#define OUT_N  (BATCH*IN_C*58*58)              // 161,472

// ---------------- Kernel P: zero-pad x ----------------
__global__ __launch_bounds__(256) void kP(const float* __restrict__ x,
                                          float* __restrict__ xpad) {
    int idx = blockIdx.x * 256 + threadIdx.x;
    if (idx >= XPAD_N) return;
    int c = idx % XPW;
    int t = idx / XPW;
    int r = t % XPH;
    t /= XPH;                       // t = b*IN_C + ci
    int rr = r - 3, cc = c - 3;
    float val = 0.0f;
    if (rr >= 0 && rr < HH && cc >= 0 && cc < WW)
        val = x[(size_t)t * (HH * WW) + rr * WW + cc];
    xpad[idx] = val;
}

// ---------------- Kernel Q: q conv -> qpad (padded, zero border) ----------------
__global__ __launch_bounds__(256) void kQ(const float* __restrict__ xpad,
                                          const float* __restrict__ Wq,
                                          const float* __restrict__ bq,
                                          float* __restrict__ qpad) {
    int idx = blockIdx.x * 256 + threadIdx.x;
    if (idx >= QPAD_N) return;
    int c = idx % QPW;
    int t = idx / QPW;
    int r = t % QPH; t /= QPH;
    int qc = t % Q_C; t /= Q_C;
    int ic = t % IN_C;
    int b  = t / IN_C;
    float out = 0.0f;
    if (r >= 3 && r < 115 && c >= 3 && c < 115) {
        int y = r - 3, x = c - 3;
        const float* wp = Wq + (size_t)(ic * Q_C + qc) * (IN_C * KK * KK);
        out = bq[ic * Q_C + qc];
        for (int ci = 0; ci < IN_C; ++ci) {
            const float* xrow = xpad + ((size_t)(b * IN_C + ci) * XPH + 2 * y) * XPW + 2 * x;
            const float* wr = wp + ci * (KK * KK);
            #pragma unroll
            for (int dy = 0; dy < KK; ++dy)
                #pragma unroll
                for (int dx = 0; dx < KK; ++dx)
                    out = fmaf(xrow[dy * XPW + dx], wr[dy * KK + dx], out);
        }
    }
    qpad[idx] = out;
}

// ---------------- Kernel V: v conv -> vpad ----------------
__global__ __launch_bounds__(256) void kV(const float* __restrict__ xpad,
                                          const float* __restrict__ Wv,
                                          const float* __restrict__ bv,
                                          float* __restrict__ vpad) {
    int idx = blockIdx.x * 256 + threadIdx.x;
    if (idx >= VPAD_N) return;
    int c = idx % QPW;
    int t = idx / QPW;
    int r = t % QPH; t /= QPH;
    int vc = t % V_C;
    int b  = t / V_C;
    float out = 0.0f;
    if (r >= 3 && r < 115 && c >= 3 && c < 115) {
        int y = r - 3, x = c - 3;
        const float* wp = Wv + (size_t)vc * (IN_C * KK * KK);
        out = bv[vc];
        for (int ci = 0; ci < IN_C; ++ci) {
            const float* xrow = xpad + ((size_t)(b * IN_C + ci) * XPH + 2 * y) * XPW + 2 * x;
            const float* wr = wp + ci * (KK * KK);
            #pragma unroll
            for (int dy = 0; dy < KK; ++dy)
                #pragma unroll
                for (int dx = 0; dx < KK; ++dx)
                    out = fmaf(xrow[dy * XPW + dx], wr[dy * KK + dx], out);
        }
    }
    vpad[idx] = out;
}

// ---------------- Kernel A: fused kmap conv + dynamic-conv reduction -> a ----------------
// One block per (b, ic, v). Each thread processes 49 groups of 8 kmap columns:
// computes kmap values in registers and immediately FMAs them against 16
// shifted q windows. Block-wide reduction at the end.
__global__ __launch_bounds__(256) void kA(const float* __restrict__ xpad,
                                          const float* __restrict__ qpad,
                                          const float* __restrict__ Wk,
                                          const float* __restrict__ bk,
                                          float* __restrict__ a_out) {
    int blk = blockIdx.x;                 // (b*IN_C + ic)*V_C + v
    int b   = blk / (IN_C * V_C);
    int rem = blk - b * (IN_C * V_C);
    int ic  = rem / V_C;
    int v   = rem - ic * V_C;
    int tid = threadIdx.x;

    __shared__ float wlds[Q_C * IN_C * KK * 8];   // [qc][ci][dy][dx(8, padded)]
    __shared__ float bk8[Q_C];
    __shared__ float red[4][16];

    const float* wk_slice = Wk + (size_t)(ic * V_C + v) * (Q_C * IN_C * KK * KK);
    for (int t = tid; t < Q_C * IN_C * KK * 8; t += 256) {
        int dx = t & 7;
        int rest = t >> 3;                 // qc*21 + ci*7 + dy
        wlds[t] = (dx < 7) ? wk_slice[rest * 7 + dx] : 0.0f;
    }
    if (tid < Q_C) bk8[tid] = bk[(ic * V_C + v) * Q_C + tid];
    __syncthreads();

    float acc[4][4];
    #pragma unroll
    for (int p = 0; p < 4; ++p)
        #pragma unroll
        for (int q = 0; q < 4; ++q) acc[p][q] = 0.0f;

    const float* xb = xpad + (size_t)b * IN_C * XPH * XPW;
    const float* qb = qpad + (size_t)(b * IN_C + ic) * Q_C * QPH * QPW;

    for (int it = 0; it < 49; ++it) {
        int g = tid + (it << 8);           // 0 .. 12543, covers qc(8) x y(112) x seg(14)
        int qc = g / 1568;
        int r1 = g - qc * 1568;
        int y  = r1 / 14;
        int seg = r1 - y * 14;             // x0 = 8*seg

        float kv[8];
        float bkv = bk8[qc];
        #pragma unroll
        for (int j = 0; j < 8; ++j) kv[j] = bkv;

        for (int ci = 0; ci < IN_C; ++ci) {
            const float* xrowbase = xb + (size_t)ci * (XPH * XPW) + (2 * y) * XPW + 16 * seg;
            const float* wbase = &wlds[((qc * IN_C + ci) * KK) * 8];
            #pragma unroll
            for (int dy = 0; dy < KK; ++dy) {
                float xr[24];
                const float* xrow = xrowbase + dy * XPW;
                #pragma unroll
                for (int m = 0; m < 6; ++m)
                    *(float4*)(&xr[4 * m]) = ((const float4*)xrow)[m];
                float w[8];
                *(float4*)(&w[0]) = ((const float4*)(wbase + dy * 8))[0];
                *(float4*)(&w[4]) = ((const float4*)(wbase + dy * 8))[1];
                #pragma unroll
                for (int dx = 0; dx < KK; ++dx)
                    #pragma unroll
                    for (int j = 0; j < 8; ++j)
                        kv[j] = fmaf(w[dx], xr[dx + 2 * j], kv[j]);
            }
        }

        // multiply kmap segment against 16 shifted q windows
        const float* qrow0 = qb + (size_t)qc * (QPH * QPW) + y * QPW + 8 * seg;
        #pragma unroll
        for (int th = 0; th < 4; ++th) {
            float qr[16];
            const float* qrow = qrow0 + th * 2 * QPW;
            #pragma unroll
            for (int m = 0; m < 4; ++m)
                *(float4*)(&qr[4 * m]) = ((const float4*)qrow)[m];
            #pragma unroll
            for (int tw = 0; tw < 4; ++tw)
                #pragma unroll
                for (int j = 0; j < 8; ++j)
                    acc[th][tw] = fmaf(kv[j], qr[2 * tw + j], acc[th][tw]);
        }
    }

    // reduce 16 accumulators across 256 threads
    int lane = tid & 63;
    int wave = tid >> 6;
    float rsum[16];
    #pragma unroll
    for (int t = 0; t < 16; ++t) {
        float s = acc[t >> 2][t & 3];
        #pragma unroll
        for (int off = 32; off; off >>= 1) s += __shfl_down(s, off, 64);
        rsum[t] = s;
    }
    if (lane == 0) {
        #pragma unroll
        for (int t = 0; t < 16; ++t) red[wave][t] = rsum[t];
    }
    __syncthreads();
    if (tid < 16) {
        float s = red[0][tid] + red[1][tid] + red[2][tid] + red[3][tid];
        a_out[(size_t)blk * 16 + tid] = s;
    }
}

// ---------------- Kernel O: final dynamic conv -> out ----------------
__global__ __launch_bounds__(256) void kO(const float* __restrict__ vpad,
                                          const float* __restrict__ a,
                                          float* __restrict__ out) {
    int idx = blockIdx.x * 256 + threadIdx.x;
    if (idx >= OUT_N) return;
    int ow = idx % 58;
    int t = idx / 58;
    int oh = t % 58; t /= 58;
    int ic = t % IN_C;
    int b  = t / IN_C;
    const float* ab = a + (size_t)(b * IN_C + ic) * (V_C * 16);
    float s = 0.0f;
    for (int vc = 0; vc < V_C; ++vc) {
        const float* vrow = vpad + ((size_t)(b * V_C + vc) * QPH + 2 * oh) * QPW + 2 * ow;
        const float* ar = ab + vc * 16;
        #pragma unroll
        for (int kh = 0; kh < 4; ++kh)
            #pragma unroll
            for (int kw = 0; kw < 4; ++kw)
                s = fmaf(vrow[kh * QPW + kw], ar[kh * 4 + kw], s);
    }
    out[idx] = s;
}

extern "C" void kernel_launch(void* const* d_in, const int* in_sizes, int n_in,
                              void* d_out, int out_size, void* d_ws, size_t ws_size,
                              hipStream_t stream) {
    (void)in_sizes; (void)n_in; (void)out_size; (void)ws_size;
    const float* x  = (const float*)d_in[0];
    const float* Wq = (const float*)d_in[1];
    const float* bq = (const float*)d_in[2];
    const float* Wk = (const float*)d_in[3];
    const float* bk = (const float*)d_in[4];
    const float* Wv = (const float*)d_in[5];
    const float* bv = (const float*)d_in[6];
    float* out = (float*)d_out;

    float* ws   = (float*)d_ws;
    float* xpad = ws;
    float* qpad = xpad + XPAD_N;
    float* vpad = qpad + QPAD_N;
    float* a    = vpad + VPAD_N;
    // total ws use: (2561280+5437440+3624960+12288)*4 = ~46.5 MB

    kP<<<(XPAD_N + 255) / 256, 256, 0, stream>>>(x, xpad);
    kQ<<<(QPAD_N + 255) / 256, 256, 0, stream>>>(xpad, Wq, bq, qpad);
    kV<<<(VPAD_N + 255) / 256, 256, 0, stream>>>(xpad, Wv, bv, vpad);
    kA<<<768, 256, 0, stream>>>(xpad, qpad, Wk, bk, a);
    kO<<<(OUT_N + 255) / 256, 256, 0, stream>>>(vpad, a, out);
}

// Round 2
// 999.545 us; speedup vs baseline: 1.7921x; 1.7921x over previous
//
#include <hip/hip_runtime.h>
#include <hip/hip_bf16.h>

// Problem constants
#define BATCH 16
#define IN_C 3
#define Q_C 8
#define V_C 16
#define HH 224
#define WW 224
#define KK 7
#define H2 112
#define W2 112

// Padded layouts
#define XPH 230   // stored row = orig row + 3
#define XPW 232   // stored col = orig col + 3
#define QPH 118   // stored = orig + 3
#define QPW 120

// Sizes (floats)
#define XPAD_N (BATCH*IN_C*XPH*XPW)            // 2,561,280
#define QPAD_N (BATCH*IN_C*Q_C*QPH*QPW)        // 5,437,440
#define VPAD_N (BATCH*V_C*QPH*QPW)             // 3,624,960
#define A_N    (BATCH*IN_C*V_C*16)             // 12,288
#define OUT_N  (BATCH*IN_C*58*58)              // 161,472

// ---------------- Kernel P: zero-pad x ----------------
__global__ __launch_bounds__(256) void kP(const float* __restrict__ x,
                                          float* __restrict__ xpad) {
    int idx = blockIdx.x * 256 + threadIdx.x;
    if (idx >= XPAD_N) return;
    int c = idx % XPW;
    int t = idx / XPW;
    int r = t % XPH;
    t /= XPH;                       // t = b*IN_C + ci
    int rr = r - 3, cc = c - 3;
    float val = 0.0f;
    if (rr >= 0 && rr < HH && cc >= 0 && cc < WW)
        val = x[(size_t)t * (HH * WW) + rr * WW + cc];
    xpad[idx] = val;
}

// ---------------- Kernel Q: q conv -> qpad (padded, zero border) ----------------
__global__ __launch_bounds__(256) void kQ(const float* __restrict__ xpad,
                                          const float* __restrict__ Wq,
                                          const float* __restrict__ bq,
                                          float* __restrict__ qpad) {
    int idx = blockIdx.x * 256 + threadIdx.x;
    if (idx >= QPAD_N) return;
    int c = idx % QPW;
    int t = idx / QPW;
    int r = t % QPH; t /= QPH;
    int qc = t % Q_C; t /= Q_C;
    int ic = t % IN_C;
    int b  = t / IN_C;
    float out = 0.0f;
    if (r >= 3 && r < 115 && c >= 3 && c < 115) {
        int y = r - 3, x = c - 3;
        const float* wp = Wq + (size_t)(ic * Q_C + qc) * (IN_C * KK * KK);
        out = bq[ic * Q_C + qc];
        for (int ci = 0; ci < IN_C; ++ci) {
            const float* xrow = xpad + ((size_t)(b * IN_C + ci) * XPH + 2 * y) * XPW + 2 * x;
            const float* wr = wp + ci * (KK * KK);
            #pragma unroll
            for (int dy = 0; dy < KK; ++dy)
                #pragma unroll
                for (int dx = 0; dx < KK; ++dx)
                    out = fmaf(xrow[dy * XPW + dx], wr[dy * KK + dx], out);
        }
    }
    qpad[idx] = out;
}

// ---------------- Kernel V: v conv -> vpad ----------------
__global__ __launch_bounds__(256) void kV(const float* __restrict__ xpad,
                                          const float* __restrict__ Wv,
                                          const float* __restrict__ bv,
                                          float* __restrict__ vpad) {
    int idx = blockIdx.x * 256 + threadIdx.x;
    if (idx >= VPAD_N) return;
    int c = idx % QPW;
    int t = idx / QPW;
    int r = t % QPH; t /= QPH;
    int vc = t % V_C;
    int b  = t / V_C;
    float out = 0.0f;
    if (r >= 3 && r < 115 && c >= 3 && c < 115) {
        int y = r - 3, x = c - 3;
        const float* wp = Wv + (size_t)vc * (IN_C * KK * KK);
        out = bv[vc];
        for (int ci = 0; ci < IN_C; ++ci) {
            const float* xrow = xpad + ((size_t)(b * IN_C + ci) * XPH + 2 * y) * XPW + 2 * x;
            const float* wr = wp + ci * (KK * KK);
            #pragma unroll
            for (int dy = 0; dy < KK; ++dy)
                #pragma unroll
                for (int dx = 0; dx < KK; ++dx)
                    out = fmaf(xrow[dy * XPW + dx], wr[dy * KK + dx], out);
        }
    }
    vpad[idx] = out;
}

// ---------------- Kernel A: fused kmap conv + dynamic-conv reduction -> a ----------------
// One block per (b, ic, v). Each thread owns (y, seg) positions; computes the
// kmap values for ALL 8 qc from ONE set of x loads (kv[8][8] in registers),
// then FMAs them against the 16 shifted q windows. 8x fewer x loads per FMA
// than the R1 version -> latency amortized, VALU stays busy.
__global__ __launch_bounds__(256, 3) void kA(const float* __restrict__ xpad,
                                             const float* __restrict__ qpad,
                                             const float* __restrict__ Wk,
                                             const float* __restrict__ bk,
                                             float* __restrict__ a_out) {
    int blk = blockIdx.x;                 // (b*IN_C + ic)*V_C + v
    int b   = blk / (IN_C * V_C);
    int rem = blk - b * (IN_C * V_C);
    int ic  = rem / V_C;
    int v   = rem - ic * V_C;
    int tid = threadIdx.x;

    __shared__ float wlds[Q_C * IN_C * KK * 8];   // [qc][ci][dy][dx(8, padded)]
    __shared__ float bk8[Q_C];
    __shared__ float red[4][16];

    const float* wk_slice = Wk + (size_t)(ic * V_C + v) * (Q_C * IN_C * KK * KK);
    for (int t = tid; t < Q_C * IN_C * KK * 8; t += 256) {
        int dx = t & 7;
        int rest = t >> 3;                 // qc*21 + ci*7 + dy
        wlds[t] = (dx < 7) ? wk_slice[rest * 7 + dx] : 0.0f;
    }
    if (tid < Q_C) bk8[tid] = bk[(ic * V_C + v) * Q_C + tid];
    __syncthreads();

    float acc[16];
    #pragma unroll
    for (int t = 0; t < 16; ++t) acc[t] = 0.0f;

    const float* xb = xpad + (size_t)b * IN_C * XPH * XPW;
    const float* qb = qpad + (size_t)(b * IN_C + ic) * Q_C * QPH * QPW;

    for (int it = 0; it < 7; ++it) {
        int g = tid + (it << 8);           // covers y(112) x seg(14) = 1568
        if (g >= 112 * 14) break;          // only last iteration partially active
        int y   = g / 14;
        int seg = g - y * 14;              // x0 = 8*seg

        // kmap values for all 8 qc at this (y, seg), 8 consecutive columns
        float kv[Q_C][8];
        #pragma unroll
        for (int qc = 0; qc < Q_C; ++qc) {
            float bkv = bk8[qc];
            #pragma unroll
            for (int j = 0; j < 8; ++j) kv[qc][j] = bkv;
        }

        for (int ci = 0; ci < IN_C; ++ci) {
            const float* xrowbase = xb + (size_t)ci * (XPH * XPW) + (2 * y) * XPW + 16 * seg;
            const float* wcibase  = &wlds[(ci * KK) * 8];
            for (int dy = 0; dy < KK; ++dy) {
                float xr[24];
                const float* xrow = xrowbase + dy * XPW;
                #pragma unroll
                for (int m = 0; m < 6; ++m)
                    *(float4*)(&xr[4 * m]) = ((const float4*)xrow)[m];
                #pragma unroll
                for (int qc = 0; qc < Q_C; ++qc) {
                    const float* wbase = wcibase + (qc * IN_C * KK + dy) * 8;
                    float w[8];
                    *(float4*)(&w[0]) = ((const float4*)wbase)[0];
                    *(float4*)(&w[4]) = ((const float4*)wbase)[1];
                    #pragma unroll
                    for (int dx = 0; dx < KK; ++dx)
                        #pragma unroll
                        for (int j = 0; j < 8; ++j)
                            kv[qc][j] = fmaf(w[dx], xr[dx + 2 * j], kv[qc][j]);
                }
            }
        }

        // multiply kmap segment against 16 shifted q windows, all 8 qc
        #pragma unroll
        for (int qc = 0; qc < Q_C; ++qc) {
            const float* qrow0 = qb + (size_t)qc * (QPH * QPW) + y * QPW + 8 * seg;
            #pragma unroll
            for (int th = 0; th < 4; ++th) {
                float qr[16];
                const float* qrow = qrow0 + th * 2 * QPW;
                #pragma unroll
                for (int m = 0; m < 4; ++m)
                    *(float4*)(&qr[4 * m]) = ((const float4*)qrow)[m];
                #pragma unroll
                for (int tw = 0; tw < 4; ++tw)
                    #pragma unroll
                    for (int j = 0; j < 8; ++j)
                        acc[th * 4 + tw] = fmaf(kv[qc][j], qr[2 * tw + j], acc[th * 4 + tw]);
            }
        }
    }

    // reduce 16 accumulators across 256 threads
    int lane = tid & 63;
    int wave = tid >> 6;
    float rsum[16];
    #pragma unroll
    for (int t = 0; t < 16; ++t) {
        float s = acc[t];
        #pragma unroll
        for (int off = 32; off; off >>= 1) s += __shfl_down(s, off, 64);
        rsum[t] = s;
    }
    if (lane == 0) {
        #pragma unroll
        for (int t = 0; t < 16; ++t) red[wave][t] = rsum[t];
    }
    __syncthreads();
    if (tid < 16) {
        float s = red[0][tid] + red[1][tid] + red[2][tid] + red[3][tid];
        a_out[(size_t)blk * 16 + tid] = s;
    }
}

// ---------------- Kernel O: final dynamic conv -> out ----------------
__global__ __launch_bounds__(256) void kO(const float* __restrict__ vpad,
                                          const float* __restrict__ a,
                                          float* __restrict__ out) {
    int idx = blockIdx.x * 256 + threadIdx.x;
    if (idx >= OUT_N) return;
    int ow = idx % 58;
    int t = idx / 58;
    int oh = t % 58; t /= 58;
    int ic = t % IN_C;
    int b  = t / IN_C;
    const float* ab = a + (size_t)(b * IN_C + ic) * (V_C * 16);
    float s = 0.0f;
    for (int vc = 0; vc < V_C; ++vc) {
        const float* vrow = vpad + ((size_t)(b * V_C + vc) * QPH + 2 * oh) * QPW + 2 * ow;
        const float* ar = ab + vc * 16;
        #pragma unroll
        for (int kh = 0; kh < 4; ++kh)
            #pragma unroll
            for (int kw = 0; kw < 4; ++kw)
                s = fmaf(vrow[kh * QPW + kw], ar[kh * 4 + kw], s);
    }
    out[idx] = s;
}

extern "C" void kernel_launch(void* const* d_in, const int* in_sizes, int n_in,
                              void* d_out, int out_size, void* d_ws, size_t ws_size,
                              hipStream_t stream) {
    (void)in_sizes; (void)n_in; (void)out_size; (void)ws_size;
    const float* x  = (const float*)d_in[0];
    const float* Wq = (const float*)d_in[1];
    const float* bq = (const float*)d_in[2];
    const float* Wk = (const float*)d_in[3];
    const float* bk = (const float*)d_in[4];
    const float* Wv = (const float*)d_in[5];
    const float* bv = (const float*)d_in[6];
    float* out = (float*)d_out;

    float* ws   = (float*)d_ws;
    float* xpad = ws;
    float* qpad = xpad + XPAD_N;
    float* vpad = qpad + QPAD_N;
    float* a    = vpad + VPAD_N;
    // total ws use: ~46.5 MB

    kP<<<(XPAD_N + 255) / 256, 256, 0, stream>>>(x, xpad);
    kQ<<<(QPAD_N + 255) / 256, 256, 0, stream>>>(xpad, Wq, bq, qpad);
    kV<<<(VPAD_N + 255) / 256, 256, 0, stream>>>(xpad, Wv, bv, vpad);
    kA<<<768, 256, 0, stream>>>(xpad, qpad, Wk, bk, a);
    kO<<<(OUT_N + 255) / 256, 256, 0, stream>>>(vpad, a, out);
}

// Round 3
// 865.468 us; speedup vs baseline: 2.0698x; 1.1549x over previous
//
#include <hip/hip_runtime.h>
#include <hip/hip_bf16.h>

// Problem constants
#define BATCH 16
#define IN_C 3
#define Q_C 8
#define V_C 16
#define HH 224
#define WW 224
#define KK 7
#define H2 112
#define W2 112

// Padded layouts
#define XPH 230   // stored row = orig row + 3
#define XPW 232   // stored col = orig col + 3
#define QPH 118   // stored = orig + 3
#define QPW 120

// Sizes (floats)
#define XPAD_N (BATCH*IN_C*XPH*XPW)            // 2,561,280
#define QPAD_N (BATCH*IN_C*Q_C*QPH*QPW)        // 5,437,440
#define VPAD_N (BATCH*V_C*QPH*QPW)             // 3,624,960
#define A_N    (BATCH*IN_C*V_C*16)             // 12,288
#define OUT_N  (BATCH*IN_C*58*58)              // 161,472

// ---------------- Kernel P: zero-pad x ----------------
__global__ __launch_bounds__(256) void kP(const float* __restrict__ x,
                                          float* __restrict__ xpad) {
    int idx = blockIdx.x * 256 + threadIdx.x;
    if (idx >= XPAD_N) return;
    int c = idx % XPW;
    int t = idx / XPW;
    int r = t % XPH;
    t /= XPH;                       // t = b*IN_C + ci
    int rr = r - 3, cc = c - 3;
    float val = 0.0f;
    if (rr >= 0 && rr < HH && cc >= 0 && cc < WW)
        val = x[(size_t)t * (HH * WW) + rr * WW + cc];
    xpad[idx] = val;
}

// ---------------- Kernel Q: q conv -> qpad (padded, zero border) ----------------
__global__ __launch_bounds__(256) void kQ(const float* __restrict__ xpad,
                                          const float* __restrict__ Wq,
                                          const float* __restrict__ bq,
                                          float* __restrict__ qpad) {
    int idx = blockIdx.x * 256 + threadIdx.x;
    if (idx >= QPAD_N) return;
    int c = idx % QPW;
    int t = idx / QPW;
    int r = t % QPH; t /= QPH;
    int qc = t % Q_C; t /= Q_C;
    int ic = t % IN_C;
    int b  = t / IN_C;
    float out = 0.0f;
    if (r >= 3 && r < 115 && c >= 3 && c < 115) {
        int y = r - 3, x = c - 3;
        const float* wp = Wq + (size_t)(ic * Q_C + qc) * (IN_C * KK * KK);
        out = bq[ic * Q_C + qc];
        for (int ci = 0; ci < IN_C; ++ci) {
            const float* xrow = xpad + ((size_t)(b * IN_C + ci) * XPH + 2 * y) * XPW + 2 * x;
            const float* wr = wp + ci * (KK * KK);
            #pragma unroll
            for (int dy = 0; dy < KK; ++dy)
                #pragma unroll
                for (int dx = 0; dx < KK; ++dx)
                    out = fmaf(xrow[dy * XPW + dx], wr[dy * KK + dx], out);
        }
    }
    qpad[idx] = out;
}

// ---------------- Kernel V: v conv -> vpad ----------------
__global__ __launch_bounds__(256) void kV(const float* __restrict__ xpad,
                                          const float* __restrict__ Wv,
                                          const float* __restrict__ bv,
                                          float* __restrict__ vpad) {
    int idx = blockIdx.x * 256 + threadIdx.x;
    if (idx >= VPAD_N) return;
    int c = idx % QPW;
    int t = idx / QPW;
    int r = t % QPH; t /= QPH;
    int vc = t % V_C;
    int b  = t / V_C;
    float out = 0.0f;
    if (r >= 3 && r < 115 && c >= 3 && c < 115) {
        int y = r - 3, x = c - 3;
        const float* wp = Wv + (size_t)vc * (IN_C * KK * KK);
        out = bv[vc];
        for (int ci = 0; ci < IN_C; ++ci) {
            const float* xrow = xpad + ((size_t)(b * IN_C + ci) * XPH + 2 * y) * XPW + 2 * x;
            const float* wr = wp + ci * (KK * KK);
            #pragma unroll
            for (int dy = 0; dy < KK; ++dy)
                #pragma unroll
                for (int dx = 0; dx < KK; ++dx)
                    out = fmaf(xrow[dy * XPW + dx], wr[dy * KK + dx], out);
        }
    }
    vpad[idx] = out;
}

// ---------------- Kernel A: fused kmap conv + dynamic-conv reduction -> a ----------------
// One block per (b, ic, v). Each thread owns (y, seg) positions. qc is
// processed in TWO HALVES of 4 so the live kmap register tile is kv[4][8]
// (32 VGPRs) instead of kv[8][8] (64) -> no scratch spill (R2 spilled 820 MB).
// x rows are re-swept once per half (L1/L2-hot, 224 FMA per 24-float row).
__global__ __launch_bounds__(256, 3) void kA(const float* __restrict__ xpad,
                                             const float* __restrict__ qpad,
                                             const float* __restrict__ Wk,
                                             const float* __restrict__ bk,
                                             float* __restrict__ a_out) {
    int blk = blockIdx.x;                 // (b*IN_C + ic)*V_C + v
    int b   = blk / (IN_C * V_C);
    int rem = blk - b * (IN_C * V_C);
    int ic  = rem / V_C;
    int v   = rem - ic * V_C;
    int tid = threadIdx.x;

    __shared__ float wlds[Q_C * IN_C * KK * 8];   // [qc][ci][dy][dx(8, padded)]
    __shared__ float bk8[Q_C];
    __shared__ float red[4][16];

    const float* wk_slice = Wk + (size_t)(ic * V_C + v) * (Q_C * IN_C * KK * KK);
    for (int t = tid; t < Q_C * IN_C * KK * 8; t += 256) {
        int dx = t & 7;
        int rest = t >> 3;                 // qc*21 + ci*7 + dy
        wlds[t] = (dx < 7) ? wk_slice[rest * 7 + dx] : 0.0f;
    }
    if (tid < Q_C) bk8[tid] = bk[(ic * V_C + v) * Q_C + tid];
    __syncthreads();

    float acc[16];
    #pragma unroll
    for (int t = 0; t < 16; ++t) acc[t] = 0.0f;

    const float* xb = xpad + (size_t)b * IN_C * XPH * XPW;
    const float* qb = qpad + (size_t)(b * IN_C + ic) * Q_C * QPH * QPW;

    for (int it = 0; it < 7; ++it) {
        int g = tid + (it << 8);           // covers y(112) x seg(14) = 1568
        if (g >= 112 * 14) break;          // only last iteration partially active
        int y   = g / 14;
        int seg = g - y * 14;              // x0 = 8*seg

        for (int half = 0; half < 2; ++half) {
            // kmap values for 4 qc at this (y, seg), 8 consecutive columns
            float kv[4][8];
            #pragma unroll
            for (int qq = 0; qq < 4; ++qq) {
                float bkv = bk8[half * 4 + qq];
                #pragma unroll
                for (int j = 0; j < 8; ++j) kv[qq][j] = bkv;
            }

            for (int ci = 0; ci < IN_C; ++ci) {
                const float* xrowbase = xb + (size_t)ci * (XPH * XPW) + (2 * y) * XPW + 16 * seg;
                const float* wcibase  = &wlds[((half * 4) * IN_C * KK + ci * KK) * 8];
                for (int dy = 0; dy < KK; ++dy) {
                    float xr[24];
                    const float* xrow = xrowbase + dy * XPW;
                    #pragma unroll
                    for (int m = 0; m < 6; ++m)
                        *(float4*)(&xr[4 * m]) = ((const float4*)xrow)[m];
                    #pragma unroll
                    for (int qq = 0; qq < 4; ++qq) {
                        const float* wbase = wcibase + (qq * IN_C * KK + dy) * 8;
                        float w[8];
                        *(float4*)(&w[0]) = ((const float4*)wbase)[0];
                        *(float4*)(&w[4]) = ((const float4*)wbase)[1];
                        #pragma unroll
                        for (int dx = 0; dx < KK; ++dx)
                            #pragma unroll
                            for (int j = 0; j < 8; ++j)
                                kv[qq][j] = fmaf(w[dx], xr[dx + 2 * j], kv[qq][j]);
                    }
                }
            }

            // multiply this half's kmap segment against 16 shifted q windows
            #pragma unroll
            for (int qq = 0; qq < 4; ++qq) {
                const float* qrow0 = qb + (size_t)(half * 4 + qq) * (QPH * QPW) + y * QPW + 8 * seg;
                #pragma unroll
                for (int th = 0; th < 4; ++th) {
                    float qr[16];
                    const float* qrow = qrow0 + th * 2 * QPW;
                    #pragma unroll
                    for (int m = 0; m < 4; ++m)
                        *(float4*)(&qr[4 * m]) = ((const float4*)qrow)[m];
                    #pragma unroll
                    for (int tw = 0; tw < 4; ++tw)
                        #pragma unroll
                        for (int j = 0; j < 8; ++j)
                            acc[th * 4 + tw] = fmaf(kv[qq][j], qr[2 * tw + j], acc[th * 4 + tw]);
                }
            }
        }
    }

    // reduce 16 accumulators across 256 threads
    int lane = tid & 63;
    int wave = tid >> 6;
    float rsum[16];
    #pragma unroll
    for (int t = 0; t < 16; ++t) {
        float s = acc[t];
        #pragma unroll
        for (int off = 32; off; off >>= 1) s += __shfl_down(s, off, 64);
        rsum[t] = s;
    }
    if (lane == 0) {
        #pragma unroll
        for (int t = 0; t < 16; ++t) red[wave][t] = rsum[t];
    }
    __syncthreads();
    if (tid < 16) {
        float s = red[0][tid] + red[1][tid] + red[2][tid] + red[3][tid];
        a_out[(size_t)blk * 16 + tid] = s;
    }
}

// ---------------- Kernel O: final dynamic conv -> out ----------------
__global__ __launch_bounds__(256) void kO(const float* __restrict__ vpad,
                                          const float* __restrict__ a,
                                          float* __restrict__ out) {
    int idx = blockIdx.x * 256 + threadIdx.x;
    if (idx >= OUT_N) return;
    int ow = idx % 58;
    int t = idx / 58;
    int oh = t % 58; t /= 58;
    int ic = t % IN_C;
    int b  = t / IN_C;
    const float* ab = a + (size_t)(b * IN_C + ic) * (V_C * 16);
    float s = 0.0f;
    for (int vc = 0; vc < V_C; ++vc) {
        const float* vrow = vpad + ((size_t)(b * V_C + vc) * QPH + 2 * oh) * QPW + 2 * ow;
        const float* ar = ab + vc * 16;
        #pragma unroll
        for (int kh = 0; kh < 4; ++kh)
            #pragma unroll
            for (int kw = 0; kw < 4; ++kw)
                s = fmaf(vrow[kh * QPW + kw], ar[kh * 4 + kw], s);
    }
    out[idx] = s;
}

extern "C" void kernel_launch(void* const* d_in, const int* in_sizes, int n_in,
                              void* d_out, int out_size, void* d_ws, size_t ws_size,
                              hipStream_t stream) {
    (void)in_sizes; (void)n_in; (void)out_size; (void)ws_size;
    const float* x  = (const float*)d_in[0];
    const float* Wq = (const float*)d_in[1];
    const float* bq = (const float*)d_in[2];
    const float* Wk = (const float*)d_in[3];
    const float* bk = (const float*)d_in[4];
    const float* Wv = (const float*)d_in[5];
    const float* bv = (const float*)d_in[6];
    float* out = (float*)d_out;

    float* ws   = (float*)d_ws;
    float* xpad = ws;
    float* qpad = xpad + XPAD_N;
    float* vpad = qpad + QPAD_N;
    float* a    = vpad + VPAD_N;
    // total ws use: ~46.5 MB

    kP<<<(XPAD_N + 255) / 256, 256, 0, stream>>>(x, xpad);
    kQ<<<(QPAD_N + 255) / 256, 256, 0, stream>>>(xpad, Wq, bq, qpad);
    kV<<<(VPAD_N + 255) / 256, 256, 0, stream>>>(xpad, Wv, bv, vpad);
    kA<<<768, 256, 0, stream>>>(xpad, qpad, Wk, bk, a);
    kO<<<(OUT_N + 255) / 256, 256, 0, stream>>>(vpad, a, out);
}

// Round 4
// 650.088 us; speedup vs baseline: 2.7555x; 1.3313x over previous
//
#include <hip/hip_runtime.h>
#include <hip/hip_bf16.h>

// Problem constants
#define BATCH 16
#define IN_C 3
#define Q_C 8
#define V_C 16
#define HH 224
#define WW 224
#define KK 7
#define H2 112
#define W2 112

// Padded layouts
#define XPH 230   // stored row = orig row + 3
#define XPW 232   // stored col = orig col + 3
#define QPH 118   // stored = orig + 3
#define QPW 120

// Sizes (floats)
#define XPAD_N (BATCH*IN_C*XPH*XPW)            // 2,561,280
#define QPAD_N (BATCH*IN_C*Q_C*QPH*QPW)        // 5,437,440
#define VPAD_N (BATCH*V_C*QPH*QPW)             // 3,624,960
#define A_N    (BATCH*IN_C*V_C*16)             // 12,288
#define OUT_N  (BATCH*IN_C*58*58)              // 161,472

// ---------------- Kernel P: zero-pad x ----------------
__global__ __launch_bounds__(256) void kP(const float* __restrict__ x,
                                          float* __restrict__ xpad) {
    int idx = blockIdx.x * 256 + threadIdx.x;
    if (idx >= XPAD_N) return;
    int c = idx % XPW;
    int t = idx / XPW;
    int r = t % XPH;
    t /= XPH;                       // t = b*IN_C + ci
    int rr = r - 3, cc = c - 3;
    float val = 0.0f;
    if (rr >= 0 && rr < HH && cc >= 0 && cc < WW)
        val = x[(size_t)t * (HH * WW) + rr * WW + cc];
    xpad[idx] = val;
}

// ---------------- Kernel QV: q conv + v conv fused, segment-vectorized ----------------
// 40 output channels total: ch 0..23 = (ic,qc) q-channels, ch 24..39 = v-channels.
// Block = (b, position-chunk, group-of-4-channels). Thread = one (y, 8-wide seg):
// per (ci,dy) row, 6 float4 x-loads feed 4ch*7dx*8 = 224 FMAs.
// Borders of qpad/vpad are zeroed by a memset before this kernel; only the
// interior (orig 112x112) is written here.
__global__ __launch_bounds__(256) void kQV(const float* __restrict__ xpad,
                                           const float* __restrict__ Wq,
                                           const float* __restrict__ bq,
                                           const float* __restrict__ Wv,
                                           const float* __restrict__ bv,
                                           float* __restrict__ qpad,
                                           float* __restrict__ vpad) {
    int blk = blockIdx.x;               // b*70 + pb*10 + grp
    int grp = blk % 10;
    int t2  = blk / 10;
    int pb  = t2 % 7;
    int b   = t2 / 7;
    int tid = threadIdx.x;

    __shared__ float wlds[4 * IN_C * KK * 8];   // [cc][ci][dy][dx pad to 8]
    __shared__ float bsh[4];

    if (tid < 84) {                     // 4*3*7 (cc,ci,dy) rows
        int cc = tid / 21, rest = tid % 21;   // rest = ci*7+dy
        int ch = 4 * grp + cc;
        const float* wsrc = (ch < 24) ? (Wq + (size_t)ch * 147)
                                      : (Wv + (size_t)(ch - 24) * 147);
        #pragma unroll
        for (int dx = 0; dx < 7; ++dx) wlds[tid * 8 + dx] = wsrc[rest * 7 + dx];
        wlds[tid * 8 + 7] = 0.0f;
    }
    if (tid < 4) {
        int ch = 4 * grp + tid;
        bsh[tid] = (ch < 24) ? bq[ch] : bv[ch - 24];
    }
    __syncthreads();

    int pos = pb * 256 + tid;           // over y(112) x seg(14) = 1568
    if (pos >= 112 * 14) return;
    int y   = pos / 14;
    int seg = pos - y * 14;             // output cols 8*seg .. 8*seg+7

    float kv[4][8];
    #pragma unroll
    for (int cc = 0; cc < 4; ++cc)
        #pragma unroll
        for (int j = 0; j < 8; ++j) kv[cc][j] = bsh[cc];

    const float* xb = xpad + (size_t)b * IN_C * XPH * XPW;
    for (int ci = 0; ci < IN_C; ++ci) {
        const float* xrowbase = xb + (size_t)ci * (XPH * XPW) + (2 * y) * XPW + 16 * seg;
        for (int dy = 0; dy < KK; ++dy) {
            float xr[24];
            const float* xrow = xrowbase + dy * XPW;
            #pragma unroll
            for (int m = 0; m < 6; ++m)
                *(float4*)(&xr[4 * m]) = ((const float4*)xrow)[m];
            #pragma unroll
            for (int cc = 0; cc < 4; ++cc) {
                const float* wbase = &wlds[((cc * IN_C + ci) * KK + dy) * 8];
                float w[8];
                *(float4*)(&w[0]) = ((const float4*)wbase)[0];
                *(float4*)(&w[4]) = ((const float4*)wbase)[1];
                #pragma unroll
                for (int dx = 0; dx < 7; ++dx)
                    #pragma unroll
                    for (int j = 0; j < 8; ++j)
                        kv[cc][j] = fmaf(w[dx], xr[dx + 2 * j], kv[cc][j]);
            }
        }
    }

    #pragma unroll
    for (int cc = 0; cc < 4; ++cc) {
        int ch = 4 * grp + cc;
        float* op;
        if (ch < 24)
            op = qpad + (((size_t)b * 24 + ch) * QPH + (y + 3)) * QPW + 8 * seg + 3;
        else
            op = vpad + (((size_t)b * 16 + (ch - 24)) * QPH + (y + 3)) * QPW + 8 * seg + 3;
        #pragma unroll
        for (int j = 0; j < 8; ++j) op[j] = kv[cc][j];
    }
}

// ---------------- Kernel A: fused kmap conv + dynamic-conv reduction -> a ----------------
// One block per (b, ic, v). Each thread owns (y, seg) positions. qc in two
// halves of 4 (kv[4][8]). launch_bounds(256,2): allow up to 256 VGPRs so the
// ~110-register live set stays resident (R3 spilled 108 MB at VGPR cap 84).
__global__ __launch_bounds__(256, 2) void kA(const float* __restrict__ xpad,
                                             const float* __restrict__ qpad,
                                             const float* __restrict__ Wk,
                                             const float* __restrict__ bk,
                                             float* __restrict__ a_out) {
    int blk = blockIdx.x;                 // (b*IN_C + ic)*V_C + v
    int b   = blk / (IN_C * V_C);
    int rem = blk - b * (IN_C * V_C);
    int ic  = rem / V_C;
    int v   = rem - ic * V_C;
    int tid = threadIdx.x;

    __shared__ float wlds[Q_C * IN_C * KK * 8];   // [qc][ci][dy][dx(8, padded)]
    __shared__ float bk8[Q_C];
    __shared__ float red[4][16];

    const float* wk_slice = Wk + (size_t)(ic * V_C + v) * (Q_C * IN_C * KK * KK);
    for (int t = tid; t < Q_C * IN_C * KK * 8; t += 256) {
        int dx = t & 7;
        int rest = t >> 3;                 // qc*21 + ci*7 + dy
        wlds[t] = (dx < 7) ? wk_slice[rest * 7 + dx] : 0.0f;
    }
    if (tid < Q_C) bk8[tid] = bk[(ic * V_C + v) * Q_C + tid];
    __syncthreads();

    float acc[16];
    #pragma unroll
    for (int t = 0; t < 16; ++t) acc[t] = 0.0f;

    const float* xb = xpad + (size_t)b * IN_C * XPH * XPW;
    const float* qb = qpad + (size_t)(b * IN_C + ic) * Q_C * QPH * QPW;

    for (int it = 0; it < 7; ++it) {
        int g = tid + (it << 8);           // covers y(112) x seg(14) = 1568
        if (g >= 112 * 14) break;          // only last iteration partially active
        int y   = g / 14;
        int seg = g - y * 14;              // x0 = 8*seg

        for (int half = 0; half < 2; ++half) {
            // kmap values for 4 qc at this (y, seg), 8 consecutive columns
            float kv[4][8];
            #pragma unroll
            for (int qq = 0; qq < 4; ++qq) {
                float bkv = bk8[half * 4 + qq];
                #pragma unroll
                for (int j = 0; j < 8; ++j) kv[qq][j] = bkv;
            }

            for (int ci = 0; ci < IN_C; ++ci) {
                const float* xrowbase = xb + (size_t)ci * (XPH * XPW) + (2 * y) * XPW + 16 * seg;
                const float* wcibase  = &wlds[((half * 4) * IN_C * KK + ci * KK) * 8];
                for (int dy = 0; dy < KK; ++dy) {
                    float xr[24];
                    const float* xrow = xrowbase + dy * XPW;
                    #pragma unroll
                    for (int m = 0; m < 6; ++m)
                        *(float4*)(&xr[4 * m]) = ((const float4*)xrow)[m];
                    #pragma unroll
                    for (int qq = 0; qq < 4; ++qq) {
                        const float* wbase = wcibase + (qq * IN_C * KK + dy) * 8;
                        float w[8];
                        *(float4*)(&w[0]) = ((const float4*)wbase)[0];
                        *(float4*)(&w[4]) = ((const float4*)wbase)[1];
                        #pragma unroll
                        for (int dx = 0; dx < KK; ++dx)
                            #pragma unroll
                            for (int j = 0; j < 8; ++j)
                                kv[qq][j] = fmaf(w[dx], xr[dx + 2 * j], kv[qq][j]);
                    }
                }
            }

            // multiply this half's kmap segment against 16 shifted q windows
            #pragma unroll
            for (int qq = 0; qq < 4; ++qq) {
                const float* qrow0 = qb + (size_t)(half * 4 + qq) * (QPH * QPW) + y * QPW + 8 * seg;
                #pragma unroll
                for (int th = 0; th < 4; ++th) {
                    float qr[16];
                    const float* qrow = qrow0 + th * 2 * QPW;
                    #pragma unroll
                    for (int m = 0; m < 4; ++m)
                        *(float4*)(&qr[4 * m]) = ((const float4*)qrow)[m];
                    #pragma unroll
                    for (int tw = 0; tw < 4; ++tw)
                        #pragma unroll
                        for (int j = 0; j < 8; ++j)
                            acc[th * 4 + tw] = fmaf(kv[qq][j], qr[2 * tw + j], acc[th * 4 + tw]);
                }
            }
        }
    }

    // reduce 16 accumulators across 256 threads
    int lane = tid & 63;
    int wave = tid >> 6;
    float rsum[16];
    #pragma unroll
    for (int t = 0; t < 16; ++t) {
        float s = acc[t];
        #pragma unroll
        for (int off = 32; off; off >>= 1) s += __shfl_down(s, off, 64);
        rsum[t] = s;
    }
    if (lane == 0) {
        #pragma unroll
        for (int t = 0; t < 16; ++t) red[wave][t] = rsum[t];
    }
    __syncthreads();
    if (tid < 16) {
        float s = red[0][tid] + red[1][tid] + red[2][tid] + red[3][tid];
        a_out[(size_t)blk * 16 + tid] = s;
    }
}

// ---------------- Kernel O: final dynamic conv -> out ----------------
__global__ __launch_bounds__(256) void kO(const float* __restrict__ vpad,
                                          const float* __restrict__ a,
                                          float* __restrict__ out) {
    int idx = blockIdx.x * 256 + threadIdx.x;
    if (idx >= OUT_N) return;
    int ow = idx % 58;
    int t = idx / 58;
    int oh = t % 58; t /= 58;
    int ic = t % IN_C;
    int b  = t / IN_C;
    const float* ab = a + (size_t)(b * IN_C + ic) * (V_C * 16);
    float s = 0.0f;
    for (int vc = 0; vc < V_C; ++vc) {
        const float* vrow = vpad + ((size_t)(b * V_C + vc) * QPH + 2 * oh) * QPW + 2 * ow;
        const float* ar = ab + vc * 16;
        #pragma unroll
        for (int kh = 0; kh < 4; ++kh)
            #pragma unroll
            for (int kw = 0; kw < 4; ++kw)
                s = fmaf(vrow[kh * QPW + kw], ar[kh * 4 + kw], s);
    }
    out[idx] = s;
}

extern "C" void kernel_launch(void* const* d_in, const int* in_sizes, int n_in,
                              void* d_out, int out_size, void* d_ws, size_t ws_size,
                              hipStream_t stream) {
    (void)in_sizes; (void)n_in; (void)out_size; (void)ws_size;
    const float* x  = (const float*)d_in[0];
    const float* Wq = (const float*)d_in[1];
    const float* bq = (const float*)d_in[2];
    const float* Wk = (const float*)d_in[3];
    const float* bk = (const float*)d_in[4];
    const float* Wv = (const float*)d_in[5];
    const float* bv = (const float*)d_in[6];
    float* out = (float*)d_out;

    float* ws   = (float*)d_ws;
    float* xpad = ws;
    float* qpad = xpad + XPAD_N;
    float* vpad = qpad + QPAD_N;
    float* a    = vpad + VPAD_N;
    // total ws use: ~46.5 MB

    kP<<<(XPAD_N + 255) / 256, 256, 0, stream>>>(x, xpad);
    // zero qpad+vpad (contiguous) so kQV only needs to write the interior
    hipMemsetAsync(qpad, 0, (size_t)(QPAD_N + VPAD_N) * sizeof(float), stream);
    kQV<<<BATCH * 7 * 10, 256, 0, stream>>>(xpad, Wq, bq, Wv, bv, qpad, vpad);
    kA<<<768, 256, 0, stream>>>(xpad, qpad, Wk, bk, a);
    kO<<<(OUT_N + 255) / 256, 256, 0, stream>>>(vpad, a, out);
}

// Round 5
// 335.377 us; speedup vs baseline: 5.3412x; 1.9384x over previous
//
#include <hip/hip_runtime.h>
#include <hip/hip_bf16.h>

// Problem constants
#define BATCH 16
#define IN_C 3
#define Q_C 8
#define V_C 16
#define HH 224
#define WW 224
#define KK 7

// Padded layouts
#define XPH 230   // stored row = orig row + 3
#define XPW 232   // stored col = orig col + 3
#define QPH 118
#define QPW 120

// Region sizes (elements)
#define XPAD_N   (BATCH*IN_C*XPH*XPW)          // 2,561,280 f32
#define PLANES_N (BATCH*7*IN_C*XPH*QPW)        // 9,273,600 bf16
#define ONES_N   27712                          // bf16 ones (row-add tolerant)
#define VPAD_N   (BATCH*V_C*QPH*QPW)           // 3,624,960 f32
#define QPADS_STRIDE (Q_C*4*QPH*QPW)           // 453,120 per (b,ic)
#define QPADS_N  (BATCH*IN_C*QPADS_STRIDE)     // 21,749,760 bf16
#define D_N      (BATCH*IN_C*128*160)          // 983,040 f32
#define A_N      (BATCH*IN_C*V_C*16)
#define OUT_N    (BATCH*IN_C*58*58)
#define ONES_OFF PLANES_N

typedef __attribute__((ext_vector_type(8))) short bf16x8;
typedef __attribute__((ext_vector_type(4))) float f32x4;

static __device__ inline unsigned short f2b(float f) {
    __hip_bfloat16 h = __float2bfloat16(f);
    return *reinterpret_cast<unsigned short*>(&h);
}

// ---------------- Kernel P: zero-pad x (fp32, for kQV) ----------------
__global__ __launch_bounds__(256) void kP(const float* __restrict__ x,
                                          float* __restrict__ xpad) {
    int idx = blockIdx.x * 256 + threadIdx.x;
    if (idx >= XPAD_N) return;
    int c = idx % XPW;
    int t = idx / XPW;
    int r = t % XPH;
    t /= XPH;
    int rr = r - 3, cc = c - 3;
    float val = 0.0f;
    if (rr >= 0 && rr < HH && cc >= 0 && cc < WW)
        val = x[(size_t)t * (HH * WW) + rr * WW + cc];
    xpad[idx] = val;
}

// ---------------- Kernel X: dx-deinterleaved bf16 planes of x + ones ----
// planes[b][dx][ci][row][k] = xpad_padded[ci][row][2k+dx] (bf16), row<230,k<120
__global__ __launch_bounds__(256) void kX(const float* __restrict__ x,
                                          unsigned short* __restrict__ planes) {
    int idx = blockIdx.x * 256 + threadIdx.x;
    if (idx >= PLANES_N + ONES_N) return;
    if (idx >= PLANES_N) { planes[idx] = 0x3F80; return; }  // bf16 1.0
    int k = idx % QPW;
    int t = idx / QPW;
    int row = t % XPH; t /= XPH;
    int ci = t % IN_C; t /= IN_C;
    int dx = t % 7;
    int b  = t / 7;
    int r = row - 3;
    int c = 2 * k + dx - 3;
    float val = 0.0f;
    if (r >= 0 && r < HH && c >= 0 && c < WW)
        val = x[((size_t)(b * IN_C + ci) * HH + r) * WW + c];
    planes[idx] = f2b(val);
}

// ---------------- Kernel QV: q conv (-> qpadS bf16 shift-copies) + v conv ----
__global__ __launch_bounds__(256) void kQV(const float* __restrict__ xpad,
                                           const float* __restrict__ Wq,
                                           const float* __restrict__ bq,
                                           const float* __restrict__ Wv,
                                           const float* __restrict__ bv,
                                           unsigned short* __restrict__ qpadS,
                                           float* __restrict__ vpad) {
    int blk = blockIdx.x;               // b*70 + pb*10 + grp
    int grp = blk % 10;
    int t2  = blk / 10;
    int pb  = t2 % 7;
    int b   = t2 / 7;
    int tid = threadIdx.x;

    __shared__ float wlds[4 * IN_C * KK * 8];
    __shared__ float bsh[4];

    if (tid < 84) {
        int cc = tid / 21, rest = tid % 21;
        int ch = 4 * grp + cc;
        const float* wsrc = (ch < 24) ? (Wq + (size_t)ch * 147)
                                      : (Wv + (size_t)(ch - 24) * 147);
        #pragma unroll
        for (int dx = 0; dx < 7; ++dx) wlds[tid * 8 + dx] = wsrc[rest * 7 + dx];
        wlds[tid * 8 + 7] = 0.0f;
    }
    if (tid < 4) {
        int ch = 4 * grp + tid;
        bsh[tid] = (ch < 24) ? bq[ch] : bv[ch - 24];
    }
    __syncthreads();

    int pos = pb * 256 + tid;
    if (pos >= 112 * 14) return;
    int y   = pos / 14;
    int seg = pos - y * 14;

    float kv[4][8];
    #pragma unroll
    for (int cc = 0; cc < 4; ++cc)
        #pragma unroll
        for (int j = 0; j < 8; ++j) kv[cc][j] = bsh[cc];

    const float* xb = xpad + (size_t)b * IN_C * XPH * XPW;
    for (int ci = 0; ci < IN_C; ++ci) {
        const float* xrowbase = xb + (size_t)ci * (XPH * XPW) + (2 * y) * XPW + 16 * seg;
        for (int dy = 0; dy < KK; ++dy) {
            float xr[24];
            const float* xrow = xrowbase + dy * XPW;
            #pragma unroll
            for (int m = 0; m < 6; ++m)
                *(float4*)(&xr[4 * m]) = ((const float4*)xrow)[m];
            #pragma unroll
            for (int cc = 0; cc < 4; ++cc) {
                const float* wbase = &wlds[((cc * IN_C + ci) * KK + dy) * 8];
                float w[8];
                *(float4*)(&w[0]) = ((const float4*)wbase)[0];
                *(float4*)(&w[4]) = ((const float4*)wbase)[1];
                #pragma unroll
                for (int dx = 0; dx < 7; ++dx)
                    #pragma unroll
                    for (int j = 0; j < 8; ++j)
                        kv[cc][j] = fmaf(w[dx], xr[dx + 2 * j], kv[cc][j]);
            }
        }
    }

    int row = y + 3, c0 = 8 * seg + 3;
    if (grp < 6) {
        // q channels: write 4 tw-shifted bf16 copies (interior only; borders memset)
        #pragma unroll
        for (int cc = 0; cc < 4; ++cc) {
            int ch = 4 * grp + cc;
            int icq = ch >> 3, qc = ch & 7;
            unsigned short* base = qpadS + (size_t)(b * IN_C + icq) * QPADS_STRIDE
                                 + (size_t)qc * 4 * QPH * QPW;
            #pragma unroll
            for (int tw = 0; tw < 4; ++tw) {
                unsigned short* bp = base + (tw * QPH + row) * QPW;
                #pragma unroll
                for (int j = 0; j < 8; ++j) {
                    int k = c0 + j - 2 * tw;
                    if (k >= 0) bp[k] = f2b(kv[cc][j]);
                }
            }
        }
    } else {
        #pragma unroll
        for (int cc = 0; cc < 4; ++cc) {
            int vc = 4 * grp + cc - 24;
            float* op = vpad + (((size_t)(b * V_C + vc)) * QPH + row) * QPW + c0;
            #pragma unroll
            for (int j = 0; j < 8; ++j) op[j] = kv[cc][j];
        }
    }
}

// ---------------- Kernel C: MFMA GEMM  D[m=(qc,t)][n=r] += Q·X ----------------
// Block = (b, ic, yc of 8 output rows). K = pos, processed y-row by y-row
// (112 pos/row, 4 Ksteps of 32 with zero-padded tail). B (im2col X) staged in
// LDS from planes; A (shifted q windows) loaded directly from qpadS global.
__global__ __launch_bounds__(256, 2) void kC(const unsigned short* __restrict__ planes,
                                             const unsigned short* __restrict__ qpadS,
                                             float* __restrict__ D) {
    int blk = blockIdx.x;
    int b  = blk / (IN_C * 14);
    int r2 = blk % (IN_C * 14);
    int ic = r2 / 14;
    int yc = r2 % 14;
    int tid = threadIdx.x;
    int w = tid >> 6, lane = tid & 63;
    int tt = lane & 15, kq = lane >> 4;
    int th = tt >> 2, tw = tt & 3;

    __shared__ uint4 smem[160 * 17];   // B tile: 160 n-rows x 136 bf16 (272 B)

    // zero the k in [112,136) pad for all 160 rows (read region [112,128) must be 0)
    for (int i = tid; i < 480; i += 256) {
        int n = i / 3, j = i % 3;
        smem[n * 17 + 14 + j] = uint4{0, 0, 0, 0};
    }

    // precompute staging chunks: c = tid + 256*i over 160n x 14 chunks(8k) = 2240
    int soff[9];
    int sdst[9];
    bool sact[9];
    #pragma unroll
    for (int i = 0; i < 9; ++i) {
        int c = tid + 256 * i;
        sact[i] = (c < 2240);
        int cc2 = sact[i] ? c : 0;
        int n = cc2 / 14;
        int k0 = (cc2 % 14) * 8;
        int off;
        if (n >= 147) {
            off = ONES_OFF + k0;               // ones column(s); values all 1.0
        } else {
            int ci = n / 49;
            int rr = n % 49;
            int dy = rr / 7;
            int dx = rr % 7;
            off = (((b * 7 + dx) * IN_C + ci) * XPH + dy) * QPW + k0;
        }
        soff[i] = off;
        sdst[i] = n * 17 + (k0 >> 3);
    }

    f32x4 acc[2][10];
    #pragma unroll
    for (int mt = 0; mt < 2; ++mt)
        #pragma unroll
        for (int nt = 0; nt < 10; ++nt)
            acc[mt][nt] = f32x4{0.f, 0.f, 0.f, 0.f};

    const unsigned short* qSbi = qpadS + (size_t)(b * IN_C + ic) * QPADS_STRIDE;
    int qc0 = 2 * w;

    for (int ry = 0; ry < 8; ++ry) {
        int yo = yc * 8 + ry;
        __syncthreads();
        #pragma unroll
        for (int i = 0; i < 9; ++i) {
            if (sact[i])
                smem[sdst[i]] = *(const uint4*)(planes + soff[i] + yo * 240);
        }
        __syncthreads();
        #pragma unroll
        for (int s = 0; s < 4; ++s) {
            int k = 32 * s + kq * 8;
            int xs = (k < 112) ? k : 96;       // clamped; multiplies B-zeros
            bf16x8 a0 = __builtin_bit_cast(bf16x8,
                *(const uint4*)(qSbi + ((qc0 * 4 + tw) * QPH + yo + 2 * th) * QPW + xs));
            bf16x8 a1 = __builtin_bit_cast(bf16x8,
                *(const uint4*)(qSbi + (((qc0 + 1) * 4 + tw) * QPH + yo + 2 * th) * QPW + xs));
            #pragma unroll
            for (int nt = 0; nt < 10; ++nt) {
                bf16x8 bf = __builtin_bit_cast(bf16x8, smem[(nt * 16 + tt) * 17 + 4 * s + kq]);
                acc[0][nt] = __builtin_amdgcn_mfma_f32_16x16x32_bf16(a0, bf, acc[0][nt], 0, 0, 0);
                acc[1][nt] = __builtin_amdgcn_mfma_f32_16x16x32_bf16(a1, bf, acc[1][nt], 0, 0, 0);
            }
        }
    }

    // epilogue: D[m][n] atomics. D layout per tile: col = lane&15, row = (lane>>4)*4+reg
    float* Dbi = D + (size_t)(b * IN_C + ic) * (128 * 160);
    int rowb = (lane >> 4) * 4;
    #pragma unroll
    for (int mt = 0; mt < 2; ++mt) {
        int m = (qc0 + mt) * 16 + rowb;
        #pragma unroll
        for (int nt = 0; nt < 10; ++nt) {
            int n = nt * 16 + tt;
            if (n < 148) {
                #pragma unroll
                for (int r = 0; r < 4; ++r)
                    atomicAdd(&Dbi[(size_t)(m + r) * 160 + n], acc[mt][nt][r]);
            }
        }
    }
}

// ---------------- Kernel E: a[v,t] = sum_{qc,r} Wk*D + sum_qc bk*D[.,147] ----
__global__ __launch_bounds__(256) void kE(const float* __restrict__ D,
                                          const float* __restrict__ Wk,
                                          const float* __restrict__ bk,
                                          float* __restrict__ a_out) {
    int bi = blockIdx.x;               // b*3 + ic
    int ic = bi % IN_C;
    int tid = threadIdx.x;
    int v = tid >> 4, t = tid & 15;
    const float* Dbi = D + (size_t)bi * (128 * 160);
    const float* WkI = Wk + (size_t)(ic * V_C + v) * (Q_C * 147);
    const float* bkI = bk + (ic * V_C + v) * Q_C;
    float s = 0.0f;
    for (int qc = 0; qc < Q_C; ++qc) {
        const float* drow = Dbi + (qc * 16 + t) * 160;
        const float* wrow = WkI + qc * 147;
        float acc = 0.0f;
        for (int r = 0; r < 147; ++r) acc = fmaf(wrow[r], drow[r], acc);
        s += acc + bkI[qc] * drow[147];
    }
    a_out[((size_t)bi * 16 + v) * 16 + t] = s;
}

// ---------------- Kernel O: final dynamic conv -> out ----------------
__global__ __launch_bounds__(256) void kO(const float* __restrict__ vpad,
                                          const float* __restrict__ a,
                                          float* __restrict__ out) {
    int idx = blockIdx.x * 256 + threadIdx.x;
    if (idx >= OUT_N) return;
    int ow = idx % 58;
    int t = idx / 58;
    int oh = t % 58; t /= 58;
    int ic = t % IN_C;
    int b  = t / IN_C;
    const float* ab = a + (size_t)(b * IN_C + ic) * (V_C * 16);
    float s = 0.0f;
    for (int vc = 0; vc < V_C; ++vc) {
        const float* vrow = vpad + ((size_t)(b * V_C + vc) * QPH + 2 * oh) * QPW + 2 * ow;
        const float* ar = ab + vc * 16;
        #pragma unroll
        for (int kh = 0; kh < 4; ++kh)
            #pragma unroll
            for (int kw = 0; kw < 4; ++kw)
                s = fmaf(vrow[kh * QPW + kw], ar[kh * 4 + kw], s);
    }
    out[idx] = s;
}

extern "C" void kernel_launch(void* const* d_in, const int* in_sizes, int n_in,
                              void* d_out, int out_size, void* d_ws, size_t ws_size,
                              hipStream_t stream) {
    (void)in_sizes; (void)n_in; (void)out_size; (void)ws_size;
    const float* x  = (const float*)d_in[0];
    const float* Wq = (const float*)d_in[1];
    const float* bq = (const float*)d_in[2];
    const float* Wk = (const float*)d_in[3];
    const float* bk = (const float*)d_in[4];
    const float* Wv = (const float*)d_in[5];
    const float* bv = (const float*)d_in[6];
    float* out = (float*)d_out;

    // ws layout (bytes):
    // [xpad f32][planes bf16][ones bf16][vpad f32][qpadS bf16][D f32][a f32]
    char* p = (char*)d_ws;
    float*          xpad   = (float*)p;                 p += (size_t)XPAD_N * 4;
    unsigned short* planes = (unsigned short*)p;        p += (size_t)(PLANES_N + ONES_N) * 2;
    float*          vpad   = (float*)p;                 p += (size_t)VPAD_N * 4;
    unsigned short* qpadS  = (unsigned short*)p;        p += (size_t)QPADS_N * 2;
    float*          D      = (float*)p;                 p += (size_t)D_N * 4;
    float*          a      = (float*)p;
    // total ~86.6 MiB

    kP<<<(XPAD_N + 255) / 256, 256, 0, stream>>>(x, xpad);
    kX<<<(PLANES_N + ONES_N + 255) / 256, 256, 0, stream>>>(x, planes);
    // zero vpad borders, qpadS borders, and D accumulators (contiguous region)
    hipMemsetAsync(vpad, 0,
                   (size_t)VPAD_N * 4 + (size_t)QPADS_N * 2 + (size_t)D_N * 4, stream);
    kQV<<<BATCH * 7 * 10, 256, 0, stream>>>(xpad, Wq, bq, Wv, bv, qpadS, vpad);
    kC<<<BATCH * IN_C * 14, 256, 0, stream>>>(planes, qpadS, D);
    kE<<<BATCH * IN_C, 256, 0, stream>>>(D, Wk, bk, a);
    kO<<<(OUT_N + 255) / 256, 256, 0, stream>>>(vpad, a, out);
}

// Round 6
// 277.211 us; speedup vs baseline: 6.4619x; 1.2098x over previous
//
#include <hip/hip_runtime.h>
#include <hip/hip_bf16.h>

// Problem constants
#define BATCH 16
#define IN_C 3
#define Q_C 8
#define V_C 16
#define HH 224
#define WW 224
#define KK 7

// Padded layouts
#define XPH 230   // stored row = orig row + 3
#define XPW 232   // stored col = orig col + 3
#define QPH 118
#define QPW 120

// Region sizes (elements)
#define XPAD_N   (BATCH*IN_C*XPH*XPW)          // 2,561,280 f32
#define PLANES_N (BATCH*7*IN_C*XPH*QPW)        // 9,273,600 bf16
#define ONES_N   27712                          // bf16 ones
#define VPAD_N   (BATCH*V_C*QPH*QPW)           // 3,624,960 f32
#define QPADS_STRIDE (Q_C*4*QPH*QPW)           // 453,120 per (b,ic)
#define QPADS_N  (BATCH*IN_C*QPADS_STRIDE)     // 21,749,760 bf16
#define D_N      (BATCH*IN_C*128*160)          // 983,040 f32
#define A_N      (BATCH*IN_C*V_C*16)
#define OUT_N    (BATCH*IN_C*58*58)
#define ONES_OFF PLANES_N

typedef __attribute__((ext_vector_type(8))) short bf16x8;
typedef __attribute__((ext_vector_type(4))) float f32x4;

static __device__ inline unsigned short f2b(float f) {
    __hip_bfloat16 h = __float2bfloat16(f);
    return *reinterpret_cast<unsigned short*>(&h);
}

// ---------------- Kernel P: zero-pad x (fp32, for kQV) ----------------
__global__ __launch_bounds__(256) void kP(const float* __restrict__ x,
                                          float* __restrict__ xpad) {
    int idx = blockIdx.x * 256 + threadIdx.x;
    if (idx >= XPAD_N) return;
    int c = idx % XPW;
    int t = idx / XPW;
    int r = t % XPH;
    t /= XPH;
    int rr = r - 3, cc = c - 3;
    float val = 0.0f;
    if (rr >= 0 && rr < HH && cc >= 0 && cc < WW)
        val = x[(size_t)t * (HH * WW) + rr * WW + cc];
    xpad[idx] = val;
}

// ---------------- Kernel X: dx-deinterleaved bf16 planes of x + ones ----
__global__ __launch_bounds__(256) void kX(const float* __restrict__ x,
                                          unsigned short* __restrict__ planes) {
    int idx = blockIdx.x * 256 + threadIdx.x;
    if (idx >= PLANES_N + ONES_N) return;
    if (idx >= PLANES_N) { planes[idx] = 0x3F80; return; }  // bf16 1.0
    int k = idx % QPW;
    int t = idx / QPW;
    int row = t % XPH; t /= XPH;
    int ci = t % IN_C; t /= IN_C;
    int dx = t % 7;
    int b  = t / 7;
    int r = row - 3;
    int c = 2 * k + dx - 3;
    float val = 0.0f;
    if (r >= 0 && r < HH && c >= 0 && c < WW)
        val = x[((size_t)(b * IN_C + ci) * HH + r) * WW + c];
    planes[idx] = f2b(val);
}

// ---------------- Kernel QV: q conv (-> qpadS bf16 shift-copies) + v conv ----
__global__ __launch_bounds__(256) void kQV(const float* __restrict__ xpad,
                                           const float* __restrict__ Wq,
                                           const float* __restrict__ bq,
                                           const float* __restrict__ Wv,
                                           const float* __restrict__ bv,
                                           unsigned short* __restrict__ qpadS,
                                           float* __restrict__ vpad) {
    int blk = blockIdx.x;               // b*70 + pb*10 + grp
    int grp = blk % 10;
    int t2  = blk / 10;
    int pb  = t2 % 7;
    int b   = t2 / 7;
    int tid = threadIdx.x;

    __shared__ float wlds[4 * IN_C * KK * 8];
    __shared__ float bsh[4];

    if (tid < 84) {
        int cc = tid / 21, rest = tid % 21;
        int ch = 4 * grp + cc;
        const float* wsrc = (ch < 24) ? (Wq + (size_t)ch * 147)
                                      : (Wv + (size_t)(ch - 24) * 147);
        #pragma unroll
        for (int dx = 0; dx < 7; ++dx) wlds[tid * 8 + dx] = wsrc[rest * 7 + dx];
        wlds[tid * 8 + 7] = 0.0f;
    }
    if (tid < 4) {
        int ch = 4 * grp + tid;
        bsh[tid] = (ch < 24) ? bq[ch] : bv[ch - 24];
    }
    __syncthreads();

    int pos = pb * 256 + tid;
    if (pos >= 112 * 14) return;
    int y   = pos / 14;
    int seg = pos - y * 14;

    float kv[4][8];
    #pragma unroll
    for (int cc = 0; cc < 4; ++cc)
        #pragma unroll
        for (int j = 0; j < 8; ++j) kv[cc][j] = bsh[cc];

    const float* xb = xpad + (size_t)b * IN_C * XPH * XPW;
    for (int ci = 0; ci < IN_C; ++ci) {
        const float* xrowbase = xb + (size_t)ci * (XPH * XPW) + (2 * y) * XPW + 16 * seg;
        for (int dy = 0; dy < KK; ++dy) {
            float xr[24];
            const float* xrow = xrowbase + dy * XPW;
            #pragma unroll
            for (int m = 0; m < 6; ++m)
                *(float4*)(&xr[4 * m]) = ((const float4*)xrow)[m];
            #pragma unroll
            for (int cc = 0; cc < 4; ++cc) {
                const float* wbase = &wlds[((cc * IN_C + ci) * KK + dy) * 8];
                float w[8];
                *(float4*)(&w[0]) = ((const float4*)wbase)[0];
                *(float4*)(&w[4]) = ((const float4*)wbase)[1];
                #pragma unroll
                for (int dx = 0; dx < 7; ++dx)
                    #pragma unroll
                    for (int j = 0; j < 8; ++j)
                        kv[cc][j] = fmaf(w[dx], xr[dx + 2 * j], kv[cc][j]);
            }
        }
    }

    int row = y + 3, c0 = 8 * seg + 3;
    if (grp < 6) {
        #pragma unroll
        for (int cc = 0; cc < 4; ++cc) {
            int ch = 4 * grp + cc;
            int icq = ch >> 3, qc = ch & 7;
            unsigned short* base = qpadS + (size_t)(b * IN_C + icq) * QPADS_STRIDE
                                 + (size_t)qc * 4 * QPH * QPW;
            #pragma unroll
            for (int tw = 0; tw < 4; ++tw) {
                unsigned short* bp = base + (tw * QPH + row) * QPW;
                #pragma unroll
                for (int j = 0; j < 8; ++j) {
                    int k = c0 + j - 2 * tw;
                    if (k >= 0) bp[k] = f2b(kv[cc][j]);
                }
            }
        }
    } else {
        #pragma unroll
        for (int cc = 0; cc < 4; ++cc) {
            int vc = 4 * grp + cc - 24;
            float* op = vpad + (((size_t)(b * V_C + vc)) * QPH + row) * QPW + c0;
            #pragma unroll
            for (int j = 0; j < 8; ++j) op[j] = kv[cc][j];
        }
    }
}

// ---------------- Kernel C: MFMA GEMM  D[m=(ic,qc,t)][n=r] += Q·X -------------
// Block = (b, yc). 512 threads / 8 waves. M = 384 (all 3 ic share one B tile —
// the R5 version staged the same B 3x). Wave w owns m-tiles w*3..w*3+2
// (tile = ic*8+qc). B staged per y-row into LDS from planes; A direct from
// qpadS. Grid swizzled (idx = yc*16 + b) so same-b blocks co-locate per XCD.
__global__ __launch_bounds__(512, 2) void kC(const unsigned short* __restrict__ planes,
                                             const unsigned short* __restrict__ qpadS,
                                             float* __restrict__ D) {
    int blk = blockIdx.x;
    int b  = blk & 15;
    int yc = blk >> 4;
    int tid = threadIdx.x;
    int w = tid >> 6, lane = tid & 63;
    int tt = lane & 15, kq = lane >> 4;
    int th = tt >> 2, tw = tt & 3;

    __shared__ uint4 smem[160 * 17];   // B tile: 160 n-rows x 136 bf16

    // zero k in [112,136) pad for all 160 rows
    if (tid < 480) {
        int n = tid / 3, j = tid % 3;
        smem[n * 17 + 14 + j] = uint4{0, 0, 0, 0};
    }

    // staging chunks: c = tid + 512*i over 160n x 14 chunks(8k) = 2240
    int soff[5];
    int sdst[5];
    bool sact[5];
    #pragma unroll
    for (int i = 0; i < 5; ++i) {
        int c = tid + 512 * i;
        sact[i] = (c < 2240);
        int cc2 = sact[i] ? c : 0;
        int n = cc2 / 14;
        int k0 = (cc2 % 14) * 8;
        int off;
        if (n >= 147) {
            off = ONES_OFF + k0;
        } else {
            int ci = n / 49;
            int rr = n % 49;
            int dy = rr / 7;
            int dx = rr % 7;
            off = (((b * 7 + dx) * IN_C + ci) * XPH + dy) * QPW + k0;
        }
        soff[i] = off;
        sdst[i] = n * 17 + (k0 >> 3);
    }

    // A base pointers for this wave's 3 (ic,qc) tiles
    const unsigned short* abase[3];
    #pragma unroll
    for (int j = 0; j < 3; ++j) {
        int tile = w * 3 + j;
        int ic = tile >> 3, qc = tile & 7;
        abase[j] = qpadS + (size_t)(b * IN_C + ic) * QPADS_STRIDE
                 + ((qc * 4 + tw) * QPH + 2 * th) * QPW;
    }

    f32x4 acc[3][10];
    #pragma unroll
    for (int j = 0; j < 3; ++j)
        #pragma unroll
        for (int nt = 0; nt < 10; ++nt)
            acc[j][nt] = f32x4{0.f, 0.f, 0.f, 0.f};

    for (int ry = 0; ry < 8; ++ry) {
        int yo = yc * 8 + ry;
        __syncthreads();
        #pragma unroll
        for (int i = 0; i < 5; ++i) {
            if (sact[i])
                smem[sdst[i]] = *(const uint4*)(planes + soff[i] + yo * 240);
        }
        __syncthreads();
        #pragma unroll
        for (int s = 0; s < 4; ++s) {
            int k = 32 * s + kq * 8;
            int xs = (k < 112) ? k : 96;       // clamped; multiplies B-zeros
            bf16x8 af[3];
            #pragma unroll
            for (int j = 0; j < 3; ++j)
                af[j] = __builtin_bit_cast(bf16x8,
                    *(const uint4*)(abase[j] + yo * QPW + xs));
            #pragma unroll
            for (int nt = 0; nt < 10; ++nt) {
                bf16x8 bf = __builtin_bit_cast(bf16x8, smem[(nt * 16 + tt) * 17 + 4 * s + kq]);
                #pragma unroll
                for (int j = 0; j < 3; ++j)
                    acc[j][nt] = __builtin_amdgcn_mfma_f32_16x16x32_bf16(af[j], bf, acc[j][nt], 0, 0, 0);
            }
        }
    }

    // epilogue: atomics into D. C/D layout: col = lane&15, row = (lane>>4)*4+reg
    int rowb = kq * 4;
    #pragma unroll
    for (int j = 0; j < 3; ++j) {
        int tile = w * 3 + j;
        int ic = tile >> 3, qc = tile & 7;
        float* Dbi = D + (size_t)(b * IN_C + ic) * (128 * 160);
        int m = qc * 16 + rowb;
        #pragma unroll
        for (int nt = 0; nt < 10; ++nt) {
            int n = nt * 16 + tt;
            if (n < 148) {
                #pragma unroll
                for (int r = 0; r < 4; ++r)
                    atomicAdd(&Dbi[(size_t)(m + r) * 160 + n], acc[j][nt][r]);
            }
        }
    }
}

// ---------------- Kernel E: a[v,t] = sum_{qc,r} Wk*D + sum_qc bk*D[.,147] ----
// Block per (b,ic,v) = 768 blocks; thread = (t, r-lane); shuffle-reduce.
__global__ __launch_bounds__(256) void kE(const float* __restrict__ D,
                                          const float* __restrict__ Wk,
                                          const float* __restrict__ bk,
                                          float* __restrict__ a_out) {
    int blk = blockIdx.x;              // (b*3+ic)*16 + v
    int bi = blk >> 4;
    int v  = blk & 15;
    int ic = bi % IN_C;
    int tid = threadIdx.x;
    int t  = tid >> 4;
    int rl = tid & 15;
    const float* Dbi = D + (size_t)bi * (128 * 160);
    const float* WkI = Wk + (size_t)(ic * V_C + v) * (Q_C * 147);
    const float* bkI = bk + (ic * V_C + v) * Q_C;
    float s = 0.0f;
    for (int qc = 0; qc < Q_C; ++qc) {
        const float* drow = Dbi + (qc * 16 + t) * 160;
        const float* wrow = WkI + qc * 147;
        #pragma unroll
        for (int j = 0; j < 10; ++j) {
            int r = rl + 16 * j;
            if (r < 147) s = fmaf(wrow[r], drow[r], s);
        }
        if (rl == 0) s = fmaf(bkI[qc], drow[147], s);
    }
    s += __shfl_down(s, 8, 64);
    s += __shfl_down(s, 4, 64);
    s += __shfl_down(s, 2, 64);
    s += __shfl_down(s, 1, 64);
    if (rl == 0) a_out[(size_t)blk * 16 + t] = s;
}

// ---------------- Kernel O: final dynamic conv -> out ----------------
__global__ __launch_bounds__(256) void kO(const float* __restrict__ vpad,
                                          const float* __restrict__ a,
                                          float* __restrict__ out) {
    int idx = blockIdx.x * 256 + threadIdx.x;
    if (idx >= OUT_N) return;
    int ow = idx % 58;
    int t = idx / 58;
    int oh = t % 58; t /= 58;
    int ic = t % IN_C;
    int b  = t / IN_C;
    const float* ab = a + (size_t)(b * IN_C + ic) * (V_C * 16);
    float s = 0.0f;
    for (int vc = 0; vc < V_C; ++vc) {
        const float* vrow = vpad + ((size_t)(b * V_C + vc) * QPH + 2 * oh) * QPW + 2 * ow;
        const float* ar = ab + vc * 16;
        #pragma unroll
        for (int kh = 0; kh < 4; ++kh)
            #pragma unroll
            for (int kw = 0; kw < 4; ++kw)
                s = fmaf(vrow[kh * QPW + kw], ar[kh * 4 + kw], s);
    }
    out[idx] = s;
}

extern "C" void kernel_launch(void* const* d_in, const int* in_sizes, int n_in,
                              void* d_out, int out_size, void* d_ws, size_t ws_size,
                              hipStream_t stream) {
    (void)in_sizes; (void)n_in; (void)out_size; (void)ws_size;
    const float* x  = (const float*)d_in[0];
    const float* Wq = (const float*)d_in[1];
    const float* bq = (const float*)d_in[2];
    const float* Wk = (const float*)d_in[3];
    const float* bk = (const float*)d_in[4];
    const float* Wv = (const float*)d_in[5];
    const float* bv = (const float*)d_in[6];
    float* out = (float*)d_out;

    char* p = (char*)d_ws;
    float*          xpad   = (float*)p;                 p += (size_t)XPAD_N * 4;
    unsigned short* planes = (unsigned short*)p;        p += (size_t)(PLANES_N + ONES_N) * 2;
    float*          vpad   = (float*)p;                 p += (size_t)VPAD_N * 4;
    unsigned short* qpadS  = (unsigned short*)p;        p += (size_t)QPADS_N * 2;
    float*          D      = (float*)p;                 p += (size_t)D_N * 4;
    float*          a      = (float*)p;
    // total ~86.6 MiB

    kP<<<(XPAD_N + 255) / 256, 256, 0, stream>>>(x, xpad);
    kX<<<(PLANES_N + ONES_N + 255) / 256, 256, 0, stream>>>(x, planes);
    // zero vpad borders, qpadS borders, and D accumulators (contiguous region)
    hipMemsetAsync(vpad, 0,
                   (size_t)VPAD_N * 4 + (size_t)QPADS_N * 2 + (size_t)D_N * 4, stream);
    kQV<<<BATCH * 7 * 10, 256, 0, stream>>>(xpad, Wq, bq, Wv, bv, qpadS, vpad);
    kC<<<14 * 16, 512, 0, stream>>>(planes, qpadS, D);
    kE<<<BATCH * IN_C * V_C, 256, 0, stream>>>(D, Wk, bk, a);
    kO<<<(OUT_N + 255) / 256, 256, 0, stream>>>(vpad, a, out);
}